// Round 2
// baseline (703.641 us; speedup 1.0000x reference)
//
#include <hip/hip_runtime.h>
#include <stdint.h>

// CrossAttention on MI355X (gfx950). fp32 I/O, bf16 MFMA compute.
//   out0 = softmax(sem@Wq1 · (syn@Wk1)^T * sc) · (syn@Wv1)   [4,2048,768] fp32
//   out1 = softmax(syn@Wq2 · (sem@Wk2)^T * sc) · (sem@Wv2)   [4,4096,768] fp32
// Pipeline: convert activations fp32->bf16; transpose+convert weights;
// one 128x128x32 bf16 MFMA GEMM (C = scale*A·Bt^T + bias) reused for
// projections / QK^T / PV (V produced transposed so every B-operand is
// n-major k-contiguous); in-place bf16 row softmax. O GEMMs store fp32.
// Workspace: 175 MB.

typedef unsigned short u16;
typedef __attribute__((ext_vector_type(8))) __bf16 bf16x8;
typedef __attribute__((ext_vector_type(4))) float f32x4;

__device__ __forceinline__ float bf2f(u16 u) {
  union { unsigned int i; float f; } x; x.i = ((unsigned int)u) << 16; return x.f;
}
__device__ __forceinline__ u16 f2bf(float f) {  // RNE
  union { float f; unsigned int i; } x; x.f = f;
  unsigned int i = x.i;
  i += 0x7fffu + ((i >> 16) & 1u);
  return (u16)(i >> 16);
}

// async global->LDS, 16B per lane. LDS dest is wave-uniform base + lane*16.
__device__ __forceinline__ void cp16(void* lds, const void* g) {
  __builtin_amdgcn_global_load_lds((__attribute__((address_space(1))) void*)g,
                                   (__attribute__((address_space(3))) void*)lds,
                                   16, 0, 0);
}

// ---------------------------------------------------------------------------
// GEMM: C[M,N] = scale * A[M,K](bf16) @ Bt[N,K](bf16)^T (+ bias fp32)
// BIAS_MODE: 0 none, 1 per-col (bias[n]), 2 per-row (bias[m])
// OUTF: 0 -> store bf16, 1 -> store fp32
// M,N multiples of 128; K multiple of 32. Batched via blockIdx.z + strides.
// ---------------------------------------------------------------------------
template <int BIAS_MODE, int OUTF>
__global__ __launch_bounds__(256)
void gemm_bt_kernel(const u16* __restrict__ A, const u16* __restrict__ Bt,
                    const float* __restrict__ bias, void* __restrict__ Cv,
                    int K, int lda, int ldb, int ldc,
                    long sAb, long sBb, long sCb, float scale)
{
  __shared__ __align__(16) u16 Asl[128 * 32];  // [m][32] rows of 64B, linear
  __shared__ __align__(16) u16 Bsl[128 * 32];  // [n][32]

  const int tid  = threadIdx.x;
  const int lane = tid & 63;
  const int wave = tid >> 6;
  const int l15  = lane & 15;
  const int quad = lane >> 4;
  const int mw   = (wave >> 1) * 64;   // wave's 64x64 quadrant
  const int nw   = (wave & 1) * 64;

  const long zb = blockIdx.z;
  const char* Ab = (const char*)(A + zb * sAb + (long)blockIdx.x * 128 * lda);
  const char* Bb = (const char*)(Bt + zb * sBb + (long)blockIdx.y * 128 * ldb);

  // Staging map: linear LDS offset o = wave*1024 + lane*16 (+4096 round 2)
  //  -> tile row o>>6 (64B rows), in-row byte o&63.
  const int o   = wave * 1024 + lane * 16;
  const int mst = o >> 6;
  const int off = o & 63;
  char* ldsA = (char*)Asl + wave * 1024;  // wave-uniform base
  char* ldsB = (char*)Bsl + wave * 1024;
  const long ldaB = (long)lda * 2;
  const long ldbB = (long)ldb * 2;
  const char* pa0 = Ab + (long)mst * ldaB + off;
  const char* pb0 = Bb + (long)mst * ldbB + off;

  f32x4 acc[4][4];
  {
    f32x4 zz = {0.f, 0.f, 0.f, 0.f};
#pragma unroll
    for (int i = 0; i < 4; ++i)
#pragma unroll
      for (int j = 0; j < 4; ++j) acc[i][j] = zz;
  }

  const int nk = K >> 5;
  for (int kk = 0; kk < nk; ++kk) {
    const long kb = (long)kk << 6;  // 32 elems * 2B
    cp16(ldsA,        pa0 + kb);
    cp16(ldsA + 4096, pa0 + kb + 64 * ldaB);
    cp16(ldsB,        pb0 + kb);
    cp16(ldsB + 4096, pb0 + kb + 64 * ldbB);
    __syncthreads();  // compiler drains vmcnt before barrier

    bf16x8 a[4], b[4];
    const bf16x8* As8 = (const bf16x8*)Asl;
    const bf16x8* Bs8 = (const bf16x8*)Bsl;
#pragma unroll
    for (int i = 0; i < 4; ++i) a[i] = As8[(mw + i * 16 + l15) * 4 + quad];
#pragma unroll
    for (int j = 0; j < 4; ++j) b[j] = Bs8[(nw + j * 16 + l15) * 4 + quad];
#pragma unroll
    for (int i = 0; i < 4; ++i)
#pragma unroll
      for (int j = 0; j < 4; ++j)
        acc[i][j] = __builtin_amdgcn_mfma_f32_16x16x32_bf16(a[i], b[j], acc[i][j], 0, 0, 0);
    __syncthreads();
  }

  // Epilogue. C/D layout (m89-verified): col = lane&15, row = quad*4 + reg.
  const int brow = blockIdx.x * 128 + mw + quad * 4;
  const int bcol = blockIdx.y * 128 + nw + l15;
  float cb[4];
  if (BIAS_MODE == 1) {
#pragma unroll
    for (int j = 0; j < 4; ++j) cb[j] = bias[bcol + j * 16];
  }
#pragma unroll
  for (int i = 0; i < 4; ++i) {
    const int r0 = brow + i * 16;
    float rb[4];
    if (BIAS_MODE == 2) {
#pragma unroll
      for (int r = 0; r < 4; ++r) rb[r] = bias[r0 + r];
    }
#pragma unroll
    for (int j = 0; j < 4; ++j) {
      const int col = bcol + j * 16;
#pragma unroll
      for (int r = 0; r < 4; ++r) {
        float x = acc[i][j][r] * scale;
        if (BIAS_MODE == 1) x += cb[j];
        if (BIAS_MODE == 2) x += rb[r];
        if (OUTF)
          ((float*)Cv)[zb * sCb + (long)(r0 + r) * ldc + col] = x;
        else
          ((u16*)Cv)[zb * sCb + (long)(r0 + r) * ldc + col] = f2bf(x);
      }
    }
  }
}

// ---------------------------------------------------------------------------
// fp32 -> bf16 convert, 8 elems/thread. n % 8 == 0.
// ---------------------------------------------------------------------------
__global__ __launch_bounds__(256)
void cvt_bf16_kernel(const float* __restrict__ src, u16* __restrict__ dst, int n8)
{
  int idx = blockIdx.x * 256 + threadIdx.x;
  if (idx >= n8) return;
  const float4* s4 = (const float4*)src;
  float4 a = s4[idx * 2], b = s4[idx * 2 + 1];
  uint4 o;
  o.x = (unsigned int)f2bf(a.x) | ((unsigned int)f2bf(a.y) << 16);
  o.y = (unsigned int)f2bf(a.z) | ((unsigned int)f2bf(a.w) << 16);
  o.z = (unsigned int)f2bf(b.x) | ((unsigned int)f2bf(b.y) << 16);
  o.w = (unsigned int)f2bf(b.z) | ((unsigned int)f2bf(b.w) << 16);
  ((uint4*)dst)[idx] = o;
}

// ---------------------------------------------------------------------------
// Transpose + convert six 768x768 fp32 weights ([in,out] -> bf16 [out,in]).
// grid (24,24,6), block (32,8).
// ---------------------------------------------------------------------------
__global__ void transpose6_kernel(const float* s0, const float* s1, const float* s2,
                                  const float* s3, const float* s4, const float* s5,
                                  u16* d0, u16* d1, u16* d2,
                                  u16* d3, u16* d4, u16* d5)
{
  __shared__ float t[32][33];
  const float* src; u16* dst;
  switch (blockIdx.z) {
    case 0: src = s0; dst = d0; break;
    case 1: src = s1; dst = d1; break;
    case 2: src = s2; dst = d2; break;
    case 3: src = s3; dst = d3; break;
    case 4: src = s4; dst = d4; break;
    default: src = s5; dst = d5; break;
  }
  const int tx = threadIdx.x, ty = threadIdx.y;
  const int x = blockIdx.x * 32 + tx;      // out-dim (h)
  const int y0 = blockIdx.y * 32;          // in-dim
#pragma unroll
  for (int j = 0; j < 32; j += 8) t[ty + j][tx] = src[(long)(y0 + ty + j) * 768 + x];
  __syncthreads();
  const int x2 = y0 + tx;
#pragma unroll
  for (int j = 0; j < 32; j += 8)
    dst[(long)(blockIdx.x * 32 + ty + j) * 768 + x2] = f2bf(t[tx][ty + j]);
}

// ---------------------------------------------------------------------------
// In-place row softmax on bf16 [rows, NV*256]. One 256-thread block per row.
// ---------------------------------------------------------------------------
template <int NV>
__global__ __launch_bounds__(256)
void softmax_kernel(u16* S)
{
  __shared__ float red[8];
  const int tid  = threadIdx.x;
  const int lane = tid & 63;
  const int wave = tid >> 6;
  uint4* p4 = (uint4*)(S + (long)blockIdx.x * (NV * 256));

  uint4 ld[NV / 8];
#pragma unroll
  for (int c = 0; c < NV / 8; ++c) ld[c] = p4[tid + c * 256];
  float v[NV];
#pragma unroll
  for (int c = 0; c < NV / 8; ++c) {
    unsigned int w[4] = {ld[c].x, ld[c].y, ld[c].z, ld[c].w};
#pragma unroll
    for (int q = 0; q < 4; ++q) {
      v[c * 8 + q * 2]     = bf2f((u16)(w[q] & 0xffffu));
      v[c * 8 + q * 2 + 1] = bf2f((u16)(w[q] >> 16));
    }
  }

  float m = -1e30f;
#pragma unroll
  for (int i = 0; i < NV; ++i) m = fmaxf(m, v[i]);
#pragma unroll
  for (int off = 32; off > 0; off >>= 1) m = fmaxf(m, __shfl_xor(m, off, 64));
  if (lane == 0) red[wave] = m;
  __syncthreads();
  m = fmaxf(fmaxf(red[0], red[1]), fmaxf(red[2], red[3]));

  float s = 0.f;
#pragma unroll
  for (int i = 0; i < NV; ++i) { v[i] = __expf(v[i] - m); s += v[i]; }
#pragma unroll
  for (int off = 32; off > 0; off >>= 1) s += __shfl_xor(s, off, 64);
  if (lane == 0) red[4 + wave] = s;
  __syncthreads();
  s = (red[4] + red[5]) + (red[6] + red[7]);
  const float inv = 1.0f / s;

#pragma unroll
  for (int c = 0; c < NV / 8; ++c) {
    unsigned int w[4];
#pragma unroll
    for (int q = 0; q < 4; ++q) {
      const u16 lo = f2bf(v[c * 8 + q * 2] * inv);
      const u16 hi = f2bf(v[c * 8 + q * 2 + 1] * inv);
      w[q] = (unsigned int)lo | ((unsigned int)hi << 16);
    }
    uint4 st; st.x = w[0]; st.y = w[1]; st.z = w[2]; st.w = w[3];
    p4[tid + c * 256] = st;
  }
}

// ---------------------------------------------------------------------------

static void launch_gemm(hipStream_t st, int mode, int outf,
                        const void* A, const void* Bt, const float* bias, void* C,
                        int M, int N, int K, int lda, int ldb, int ldc,
                        long sA, long sB, long sC, int nb, float scale)
{
  dim3 g(M / 128, N / 128, nb), b(256, 1, 1);
  const u16* Au = (const u16*)A;
  const u16* Bu = (const u16*)Bt;
  if (outf == 0) {
    if (mode == 0)
      gemm_bt_kernel<0, 0><<<g, b, 0, st>>>(Au, Bu, bias, C, K, lda, ldb, ldc, sA, sB, sC, scale);
    else if (mode == 1)
      gemm_bt_kernel<1, 0><<<g, b, 0, st>>>(Au, Bu, bias, C, K, lda, ldb, ldc, sA, sB, sC, scale);
    else
      gemm_bt_kernel<2, 0><<<g, b, 0, st>>>(Au, Bu, bias, C, K, lda, ldb, ldc, sA, sB, sC, scale);
  } else {
    if (mode == 0)
      gemm_bt_kernel<0, 1><<<g, b, 0, st>>>(Au, Bu, bias, C, K, lda, ldb, ldc, sA, sB, sC, scale);
    else if (mode == 1)
      gemm_bt_kernel<1, 1><<<g, b, 0, st>>>(Au, Bu, bias, C, K, lda, ldb, ldc, sA, sB, sC, scale);
    else
      gemm_bt_kernel<2, 1><<<g, b, 0, st>>>(Au, Bu, bias, C, K, lda, ldb, ldc, sA, sB, sC, scale);
  }
}

extern "C" void kernel_launch(void* const* d_in, const int* in_sizes, int n_in,
                              void* d_out, int out_size, void* d_ws, size_t ws_size,
                              hipStream_t stream)
{
  (void)in_sizes; (void)n_in; (void)out_size; (void)ws_size;
  const float* syn = (const float*)d_in[0];   // [4,4096,768] fp32
  const float* sem = (const float*)d_in[1];   // [4,2048,768] fp32
  const float* W[6]    = {(const float*)d_in[2], (const float*)d_in[4],  (const float*)d_in[6],
                          (const float*)d_in[8], (const float*)d_in[10], (const float*)d_in[12]};
  const float* bias[6] = {(const float*)d_in[3], (const float*)d_in[5],  (const float*)d_in[7],
                          (const float*)d_in[9], (const float*)d_in[11], (const float*)d_in[13]};
  float* out = (float*)d_out;

  // workspace layout (u16 elements), total 87,425,024 elems = 175 MB
  u16* ws   = (u16*)d_ws;
  u16* WT   = ws;                     //  3538944 (6 x 589824)
  u16* synb = ws + 3538944;           // 12582912
  u16* semb = synb + 12582912;        //  6291456
  u16* bufA = semb + 6291456;         // 12582912  (K1, then Q2)
  u16* bufB = bufA + 12582912;        // 12582912  (V1T, then V2T)
  u16* bufC = bufB + 12582912;        //  6291456  (Q1, then K2)
  u16* S    = bufC + 6291456;         // 33554432  (S1/P1, then S2/P2)

  const float SC = 0.036084391824351615f;  // 768^-0.5

  cvt_bf16_kernel<<<dim3(6144), dim3(256), 0, stream>>>(syn, synb, 1572864);
  cvt_bf16_kernel<<<dim3(3072), dim3(256), 0, stream>>>(sem, semb, 786432);
  transpose6_kernel<<<dim3(24, 24, 6), dim3(32, 8, 1), 0, stream>>>(
      W[0], W[1], W[2], W[3], W[4], W[5],
      WT + 0 * 589824, WT + 1 * 589824, WT + 2 * 589824,
      WT + 3 * 589824, WT + 4 * 589824, WT + 5 * 589824);

  // ---- attention 1: queries=semantic, keys/values=syntactic ----
  // K1 = syn @ Wk1 + bk1                       [16384 x 768] bf16
  launch_gemm(stream, 1, 0, synb, WT + 1 * 589824, bias[1], bufA,
              16384, 768, 768, 768, 768, 768, 0, 0, 0, 1, 1.f);
  // V1T = Wv1^T @ syn^T + bv1(row)             [768 x 16384] bf16
  launch_gemm(stream, 2, 0, WT + 2 * 589824, synb, bias[2], bufB,
              768, 16384, 768, 768, 768, 16384, 0, 0, 0, 1, 1.f);
  // Q1 = sem @ Wq1 + bq1                       [8192 x 768] bf16
  launch_gemm(stream, 1, 0, semb, WT + 0 * 589824, bias[0], bufC,
              8192, 768, 768, 768, 768, 768, 0, 0, 0, 1, 1.f);
  // S1 = Q1 K1^T * sc                          [4][2048 x 4096] bf16
  launch_gemm(stream, 0, 0, bufC, bufA, nullptr, S,
              2048, 4096, 768, 768, 768, 4096,
              2048L * 768, 4096L * 768, 2048L * 4096, 4, SC);
  softmax_kernel<16><<<dim3(8192), dim3(256), 0, stream>>>(S);
  // O1 = P1 @ V1                               [4][2048 x 768] fp32 -> out
  launch_gemm(stream, 0, 1, S, bufB, nullptr, out,
              2048, 768, 4096, 4096, 16384, 768,
              2048L * 4096, 4096L, 2048L * 768, 4, 1.f);

  // ---- attention 2: queries=syntactic, keys/values=semantic ----
  // Q2 = syn @ Wq2 + bq2                       [16384 x 768] bf16
  launch_gemm(stream, 1, 0, synb, WT + 3 * 589824, bias[3], bufA,
              16384, 768, 768, 768, 768, 768, 0, 0, 0, 1, 1.f);
  // K2 = sem @ Wk2 + bk2                       [8192 x 768] bf16
  launch_gemm(stream, 1, 0, semb, WT + 4 * 589824, bias[4], bufC,
              8192, 768, 768, 768, 768, 768, 0, 0, 0, 1, 1.f);
  // V2T = Wv2^T @ sem^T + bv2(row)             [768 x 8192] bf16
  launch_gemm(stream, 2, 0, WT + 5 * 589824, semb, bias[5], bufB,
              768, 8192, 768, 768, 768, 8192, 0, 0, 0, 1, 1.f);
  // S2 = Q2 K2^T * sc                          [4][4096 x 2048] bf16
  launch_gemm(stream, 0, 0, bufA, bufC, nullptr, S,
              4096, 2048, 768, 768, 768, 2048,
              4096L * 768, 2048L * 768, 4096L * 2048, 4, SC);
  softmax_kernel<8><<<dim3(16384), dim3(256), 0, stream>>>(S);
  // O2 = P2 @ V2                               [4][4096 x 768] fp32 -> out+off
  launch_gemm(stream, 0, 1, S, bufB, nullptr, out + 6291456,
              4096, 768, 2048, 2048, 8192, 768,
              4096L * 2048, 2048L, 4096L * 768, 4, 1.f);
}

// Round 3
// 650.261 us; speedup vs baseline: 1.0821x; 1.0821x over previous
//
#include <hip/hip_runtime.h>
#include <stdint.h>

// CrossAttention on MI355X (gfx950). fp32 I/O, bf16 MFMA compute.
// Round 3: multi-GEMM dispatcher — merge grid-starved GEMMs into big
// launches (PROJ x6; O1+S2 fused). Q2/K2 parked in d_out's out1 region.
// ws usage: 171.97 MB (validated <= 174.85 MB).

typedef unsigned short u16;
typedef __attribute__((ext_vector_type(8))) __bf16 bf16x8;
typedef __attribute__((ext_vector_type(4))) float f32x4;

__device__ __forceinline__ float bf2f(u16 u) {
  union { unsigned int i; float f; } x; x.i = ((unsigned int)u) << 16; return x.f;
}
__device__ __forceinline__ u16 f2bf(float f) {  // RNE
  union { float f; unsigned int i; } x; x.f = f;
  unsigned int i = x.i;
  i += 0x7fffu + ((i >> 16) & 1u);
  return (u16)(i >> 16);
}

// async global->LDS, 16B per lane. LDS dest is wave-uniform base + lane*16.
__device__ __forceinline__ void cp16(void* lds, const void* g) {
  __builtin_amdgcn_global_load_lds((__attribute__((address_space(1))) void*)g,
                                   (__attribute__((address_space(3))) void*)lds,
                                   16, 0, 0);
}

// ---------------------------------------------------------------------------
// Multi-GEMM: each block picks a descriptor by linear block id, then runs the
// m97-style 128x128x32 bf16 tile. C = scale*A·Bt^T (+bias); bf16 or fp32 out.
// mode: 0 none, 1 bias per-col, 2 bias per-row. M,N mult of 128, K mult of 32.
// ---------------------------------------------------------------------------
struct GemmDesc {
  const u16* A; const u16* Bt; const float* bias; void* C;
  long sA, sB, sC;          // batch strides (elements)
  int K, lda, ldb, ldc;
  int gx, gy;               // block grid (z implied)
  int start;                // first linear block id of this segment
  int mode, outf;           // bias mode; 0 = bf16 out, 1 = fp32 out
  float scale;
};
struct GemmPack { GemmDesc d[6]; int nd; };

__global__ __launch_bounds__(256)
void gemm_multi_kernel(GemmPack p)
{
  __shared__ __align__(16) u16 Asl[128 * 32];  // [m][32] rows of 64B, linear
  __shared__ __align__(16) u16 Bsl[128 * 32];  // [n][32]

  // segment select (scalar-uniform)
  int seg = 0;
#pragma unroll
  for (int t = 1; t < 6; ++t)
    if (t < p.nd && (int)blockIdx.x >= p.d[t].start) seg = t;
  const GemmDesc& g = p.d[seg];
  const int local = (int)blockIdx.x - g.start;
  const int pxy = g.gx * g.gy;
  const int bz = local / pxy;
  const int rem = local - bz * pxy;
  const int by = rem / g.gx;
  const int bx = rem - by * g.gx;

  const int tid  = threadIdx.x;
  const int lane = tid & 63;
  const int wave = tid >> 6;
  const int l15  = lane & 15;
  const int quad = lane >> 4;
  const int mw   = (wave >> 1) * 64;   // wave's 64x64 quadrant
  const int nw   = (wave & 1) * 64;

  const char* Ab = (const char*)(g.A + (long)bz * g.sA + (long)bx * 128 * g.lda);
  const char* Bb = (const char*)(g.Bt + (long)bz * g.sB + (long)by * 128 * g.ldb);

  // staging map: linear LDS offset o = wave*1024 + lane*16 (+4096 round 2)
  const int o   = wave * 1024 + lane * 16;
  const int mst = o >> 6;
  const int off = o & 63;
  char* ldsA = (char*)Asl + wave * 1024;  // wave-uniform base
  char* ldsB = (char*)Bsl + wave * 1024;
  const long ldaB = (long)g.lda * 2;
  const long ldbB = (long)g.ldb * 2;
  const char* pa0 = Ab + (long)mst * ldaB + off;
  const char* pb0 = Bb + (long)mst * ldbB + off;

  f32x4 acc[4][4];
  {
    f32x4 zz = {0.f, 0.f, 0.f, 0.f};
#pragma unroll
    for (int i = 0; i < 4; ++i)
#pragma unroll
      for (int j = 0; j < 4; ++j) acc[i][j] = zz;
  }

  const int nk = g.K >> 5;
  for (int kk = 0; kk < nk; ++kk) {
    const long kb = (long)kk << 6;  // 32 elems * 2B
    cp16(ldsA,        pa0 + kb);
    cp16(ldsA + 4096, pa0 + kb + 64 * ldaB);
    cp16(ldsB,        pb0 + kb);
    cp16(ldsB + 4096, pb0 + kb + 64 * ldbB);
    __syncthreads();

    bf16x8 a[4], b[4];
    const bf16x8* As8 = (const bf16x8*)Asl;
    const bf16x8* Bs8 = (const bf16x8*)Bsl;
#pragma unroll
    for (int i = 0; i < 4; ++i) a[i] = As8[(mw + i * 16 + l15) * 4 + quad];
#pragma unroll
    for (int j = 0; j < 4; ++j) b[j] = Bs8[(nw + j * 16 + l15) * 4 + quad];
#pragma unroll
    for (int i = 0; i < 4; ++i)
#pragma unroll
      for (int j = 0; j < 4; ++j)
        acc[i][j] = __builtin_amdgcn_mfma_f32_16x16x32_bf16(a[i], b[j], acc[i][j], 0, 0, 0);
    __syncthreads();
  }

  // Epilogue. C/D layout (m89): col = lane&15, row = quad*4 + reg.
  const int brow = bx * 128 + mw + quad * 4;
  const int bcol = by * 128 + nw + l15;
  float cb[4];
  if (g.mode == 1) {
#pragma unroll
    for (int j = 0; j < 4; ++j) cb[j] = g.bias[bcol + j * 16];
  }
#pragma unroll
  for (int i = 0; i < 4; ++i) {
    const int r0 = brow + i * 16;
    float rb[4];
    if (g.mode == 2) {
#pragma unroll
      for (int r = 0; r < 4; ++r) rb[r] = g.bias[r0 + r];
    }
#pragma unroll
    for (int j = 0; j < 4; ++j) {
      const int col = bcol + j * 16;
#pragma unroll
      for (int r = 0; r < 4; ++r) {
        float x = acc[i][j][r] * g.scale;
        if (g.mode == 1) x += cb[j];
        if (g.mode == 2) x += rb[r];
        const long idx = (long)bz * g.sC + (long)(r0 + r) * g.ldc + col;
        if (g.outf) ((float*)g.C)[idx] = x;
        else        ((u16*)g.C)[idx] = f2bf(x);
      }
    }
  }
}

// ---------------------------------------------------------------------------
// fp32 -> bf16 convert for two tensors in one launch. 8 elems/thread.
// ---------------------------------------------------------------------------
__global__ __launch_bounds__(256)
void cvt2_bf16_kernel(const float* __restrict__ sa, u16* __restrict__ da, int n8a,
                      const float* __restrict__ sb, u16* __restrict__ db, int n8b)
{
  int idx = blockIdx.x * 256 + threadIdx.x;
  const float* src; u16* dst; int i;
  if (idx < n8a) { src = sa; dst = da; i = idx; }
  else           { src = sb; dst = db; i = idx - n8a; if (i >= n8b) return; }
  const float4* s4 = (const float4*)src;
  float4 a = s4[i * 2], b = s4[i * 2 + 1];
  uint4 o;
  o.x = (unsigned int)f2bf(a.x) | ((unsigned int)f2bf(a.y) << 16);
  o.y = (unsigned int)f2bf(a.z) | ((unsigned int)f2bf(a.w) << 16);
  o.z = (unsigned int)f2bf(b.x) | ((unsigned int)f2bf(b.y) << 16);
  o.w = (unsigned int)f2bf(b.z) | ((unsigned int)f2bf(b.w) << 16);
  ((uint4*)dst)[i] = o;
}

// ---------------------------------------------------------------------------
// Transpose + convert six 768x768 fp32 weights ([in,out] -> bf16 [out,in]).
// ---------------------------------------------------------------------------
__global__ void transpose6_kernel(const float* s0, const float* s1, const float* s2,
                                  const float* s3, const float* s4, const float* s5,
                                  u16* d0, u16* d1, u16* d2,
                                  u16* d3, u16* d4, u16* d5)
{
  __shared__ float t[32][33];
  const float* src; u16* dst;
  switch (blockIdx.z) {
    case 0: src = s0; dst = d0; break;
    case 1: src = s1; dst = d1; break;
    case 2: src = s2; dst = d2; break;
    case 3: src = s3; dst = d3; break;
    case 4: src = s4; dst = d4; break;
    default: src = s5; dst = d5; break;
  }
  const int tx = threadIdx.x, ty = threadIdx.y;
  const int x = blockIdx.x * 32 + tx;
  const int y0 = blockIdx.y * 32;
#pragma unroll
  for (int j = 0; j < 32; j += 8) t[ty + j][tx] = src[(long)(y0 + ty + j) * 768 + x];
  __syncthreads();
  const int x2 = y0 + tx;
#pragma unroll
  for (int j = 0; j < 32; j += 8)
    dst[(long)(blockIdx.x * 32 + ty + j) * 768 + x2] = f2bf(t[tx][ty + j]);
}

// ---------------------------------------------------------------------------
// In-place row softmax on bf16 [rows, NV*256]. One 256-thread block per row.
// ---------------------------------------------------------------------------
template <int NV>
__global__ __launch_bounds__(256)
void softmax_kernel(u16* S)
{
  __shared__ float red[8];
  const int tid  = threadIdx.x;
  const int lane = tid & 63;
  const int wave = tid >> 6;
  uint4* p4 = (uint4*)(S + (long)blockIdx.x * (NV * 256));

  uint4 ld[NV / 8];
#pragma unroll
  for (int c = 0; c < NV / 8; ++c) ld[c] = p4[tid + c * 256];
  float v[NV];
#pragma unroll
  for (int c = 0; c < NV / 8; ++c) {
    unsigned int w[4] = {ld[c].x, ld[c].y, ld[c].z, ld[c].w};
#pragma unroll
    for (int q = 0; q < 4; ++q) {
      v[c * 8 + q * 2]     = bf2f((u16)(w[q] & 0xffffu));
      v[c * 8 + q * 2 + 1] = bf2f((u16)(w[q] >> 16));
    }
  }

  float m = -1e30f;
#pragma unroll
  for (int i = 0; i < NV; ++i) m = fmaxf(m, v[i]);
#pragma unroll
  for (int off = 32; off > 0; off >>= 1) m = fmaxf(m, __shfl_xor(m, off, 64));
  if (lane == 0) red[wave] = m;
  __syncthreads();
  m = fmaxf(fmaxf(red[0], red[1]), fmaxf(red[2], red[3]));

  float s = 0.f;
#pragma unroll
  for (int i = 0; i < NV; ++i) { v[i] = __expf(v[i] - m); s += v[i]; }
#pragma unroll
  for (int off = 32; off > 0; off >>= 1) s += __shfl_xor(s, off, 64);
  if (lane == 0) red[4 + wave] = s;
  __syncthreads();
  s = (red[4] + red[5]) + (red[6] + red[7]);
  const float inv = 1.0f / s;

#pragma unroll
  for (int c = 0; c < NV / 8; ++c) {
    unsigned int w[4];
#pragma unroll
    for (int q = 0; q < 4; ++q) {
      const u16 lo = f2bf(v[c * 8 + q * 2] * inv);
      const u16 hi = f2bf(v[c * 8 + q * 2 + 1] * inv);
      w[q] = (unsigned int)lo | ((unsigned int)hi << 16);
    }
    uint4 st; st.x = w[0]; st.y = w[1]; st.z = w[2]; st.w = w[3];
    p4[tid + c * 256] = st;
  }
}

// ---------------------------------------------------------------------------

static GemmDesc mkdesc(const void* A, const void* Bt, const float* bias, void* C,
                       long sA, long sB, long sC, int K, int lda, int ldb, int ldc,
                       int M, int N, int nb, int start, int mode, int outf, float scale)
{
  GemmDesc d;
  d.A = (const u16*)A; d.Bt = (const u16*)Bt; d.bias = bias; d.C = C;
  d.sA = sA; d.sB = sB; d.sC = sC;
  d.K = K; d.lda = lda; d.ldb = ldb; d.ldc = ldc;
  d.gx = M / 128; d.gy = N / 128; d.start = start;
  d.mode = mode; d.outf = outf; d.scale = scale;
  (void)nb;
  return d;
}

extern "C" void kernel_launch(void* const* d_in, const int* in_sizes, int n_in,
                              void* d_out, int out_size, void* d_ws, size_t ws_size,
                              hipStream_t stream)
{
  (void)in_sizes; (void)n_in; (void)out_size; (void)ws_size;
  const float* syn = (const float*)d_in[0];   // [4,4096,768] fp32
  const float* sem = (const float*)d_in[1];   // [4,2048,768] fp32
  const float* W[6]    = {(const float*)d_in[2], (const float*)d_in[4],  (const float*)d_in[6],
                          (const float*)d_in[8], (const float*)d_in[10], (const float*)d_in[12]};
  const float* bias[6] = {(const float*)d_in[3], (const float*)d_in[5],  (const float*)d_in[7],
                          (const float*)d_in[9], (const float*)d_in[11], (const float*)d_in[13]};
  float* out = (float*)d_out;

  // ws arena (u16 offsets), total 85,983,232 u16 = 171.97 MB
  u16* ws   = (u16*)d_ws;
  u16* WT   = ws;                       // [0, 3538944)           dead after PROJ
  u16* synb = ws + 3538944;             // [.., 16121856)         dead after PROJ
  u16* semb = ws + 16121856;            // [.., 22413312)         dead after PROJ
  u16* S1   = ws;                       // [0, 33554432)          overlaps temps (ok)
  u16* K1   = ws + 33554432;            // [.., 46137344)         dead after S1
  u16* Q1   = ws + 46137344;            // [.., 52428800)         dead after S1
  u16* S2   = ws + 33554432;            // [.., 67108864)         overlaps K1/Q1 (ok)
  u16* V1T  = ws + 67108864;            // [.., 79691776)         until O1
  u16* V2T  = ws + 79691776;            // [.., 85983232)         until O2
  // Q2/K2 live in d_out's out1 region (written long before O2 overwrites it)
  u16* Q2   = (u16*)(out + 6291456);    // 12,582,912 elems
  u16* K2   = Q2 + 12582912;            //  6,291,456 elems

  const float SC = 0.036084391824351615f;  // 768^-0.5

  // 1) fp32 -> bf16 converts (one launch)
  cvt2_bf16_kernel<<<dim3(9216), dim3(256), 0, stream>>>(
      syn, synb, 1572864, sem, semb, 786432);

  // 2) weight transpose+convert
  transpose6_kernel<<<dim3(24, 24, 6), dim3(32, 8, 1), 0, stream>>>(
      W[0], W[1], W[2], W[3], W[4], W[5],
      WT + 0 * 589824, WT + 1 * 589824, WT + 2 * 589824,
      WT + 3 * 589824, WT + 4 * 589824, WT + 5 * 589824);

  // 3) PROJ: all six projections in one launch (3456 blocks)
  {
    GemmPack p; p.nd = 6;
    // K1 = syn @ Wk1 + bk1            [16384 x 768]
    p.d[0] = mkdesc(synb, WT + 1 * 589824, bias[1], K1, 0, 0, 0,
                    768, 768, 768, 768, 16384, 768, 1, 0, 1, 0, 1.f);
    // Q2 = syn @ Wq2 + bq2            [16384 x 768] -> d_out(out1)
    p.d[1] = mkdesc(synb, WT + 3 * 589824, bias[3], Q2, 0, 0, 0,
                    768, 768, 768, 768, 16384, 768, 1, 768, 1, 0, 1.f);
    // V1T = Wv1^T @ syn^T + bv1(row)  [768 x 16384]
    p.d[2] = mkdesc(WT + 2 * 589824, synb, bias[2], V1T, 0, 0, 0,
                    768, 768, 768, 16384, 768, 16384, 1, 1536, 2, 0, 1.f);
    // Q1 = sem @ Wq1 + bq1            [8192 x 768]
    p.d[3] = mkdesc(semb, WT + 0 * 589824, bias[0], Q1, 0, 0, 0,
                    768, 768, 768, 768, 8192, 768, 1, 2304, 1, 0, 1.f);
    // K2 = sem @ Wk2 + bk2            [8192 x 768] -> d_out(out1)
    p.d[4] = mkdesc(semb, WT + 4 * 589824, bias[4], K2, 0, 0, 0,
                    768, 768, 768, 768, 8192, 768, 1, 2688, 1, 0, 1.f);
    // V2T = Wv2^T @ sem^T + bv2(row)  [768 x 8192]
    p.d[5] = mkdesc(WT + 5 * 589824, semb, bias[5], V2T, 0, 0, 0,
                    768, 768, 768, 8192, 768, 8192, 1, 3072, 2, 0, 1.f);
    gemm_multi_kernel<<<dim3(3456), dim3(256), 0, stream>>>(p);
  }

  // 4) S1 = Q1 K1^T * sc              [4][2048 x 4096] (2048 blocks)
  {
    GemmPack p; p.nd = 1;
    p.d[0] = mkdesc(Q1, K1, nullptr, S1,
                    1572864L, 3145728L, 8388608L,
                    768, 768, 768, 4096, 2048, 4096, 4, 0, 0, 0, SC);
    gemm_multi_kernel<<<dim3(2048), dim3(256), 0, stream>>>(p);
  }

  // 5) softmax over S1 rows
  softmax_kernel<16><<<dim3(8192), dim3(256), 0, stream>>>(S1);

  // 6) O1 (-> out0, fp32) fused with S2 (2432 blocks)
  {
    GemmPack p; p.nd = 2;
    // O1 = P1 @ V1                    [4][2048 x 768] fp32
    p.d[0] = mkdesc(S1, V1T, nullptr, out,
                    8388608L, 4096L, 1572864L,
                    4096, 4096, 16384, 768, 2048, 768, 4, 0, 0, 1, 1.f);
    // S2 = Q2 K2^T * sc               [4][4096 x 2048]
    p.d[1] = mkdesc(Q2, K2, nullptr, S2,
                    3145728L, 1572864L, 8388608L,
                    768, 768, 768, 2048, 4096, 2048, 4, 384, 0, 0, SC);
    gemm_multi_kernel<<<dim3(2432), dim3(256), 0, stream>>>(p);
  }

  // 7) softmax over S2 rows
  softmax_kernel<8><<<dim3(16384), dim3(256), 0, stream>>>(S2);

  // 8) O2 = P2 @ V2 -> out1, fp32 (768 blocks)
  {
    GemmPack p; p.nd = 1;
    p.d[0] = mkdesc(S2, V2T, nullptr, out + 6291456,
                    8388608L, 2048L, 3145728L,
                    2048, 2048, 8192, 768, 4096, 768, 4, 0, 0, 1, 1.f);
    gemm_multi_kernel<<<dim3(768), dim3(256), 0, stream>>>(p);
  }
}

// Round 4
// 633.734 us; speedup vs baseline: 1.1103x; 1.0261x over previous
//
#include <hip/hip_runtime.h>
#include <stdint.h>

// CrossAttention on MI355X (gfx950). fp32 I/O, bf16 MFMA compute.
// Round 4: (a) XOR-swizzled LDS layout -> 2-way (free) bank access in the
// GEMM inner loop; (b) chain-interleaved schedule: PROJx6 -> S1+S2 ->
// softmax(both) -> O1+O2. K1 parked in out0; Q2/K2/V2T parked in out1;
// V2T copied to ws before D6. Peak ws 171.97 MB.

typedef unsigned short u16;
typedef __attribute__((ext_vector_type(8))) __bf16 bf16x8;
typedef __attribute__((ext_vector_type(4))) float f32x4;

__device__ __forceinline__ float bf2f(u16 u) {
  union { unsigned int i; float f; } x; x.i = ((unsigned int)u) << 16; return x.f;
}
__device__ __forceinline__ u16 f2bf(float f) {  // RNE
  union { float f; unsigned int i; } x; x.f = f;
  unsigned int i = x.i;
  i += 0x7fffu + ((i >> 16) & 1u);
  return (u16)(i >> 16);
}

// async global->LDS, 16B per lane. LDS dest is wave-uniform base + lane*16.
__device__ __forceinline__ void cp16(void* lds, const void* g) {
  __builtin_amdgcn_global_load_lds((__attribute__((address_space(1))) void*)g,
                                   (__attribute__((address_space(3))) void*)lds,
                                   16, 0, 0);
}

// ---------------------------------------------------------------------------
// Multi-GEMM: each block picks a descriptor by linear block id, then runs the
// m97-style 128x128x32 bf16 tile. C = scale*A·Bt^T (+bias); bf16 or fp32 out.
// LDS rows are 64 B; chunk c of row r is stored at position c ^ s(r),
// s(r) = (r + (r>>2)) & 3  -> conflict-free (2-way) ds_read_b128.
// ---------------------------------------------------------------------------
struct GemmDesc {
  const u16* A; const u16* Bt; const float* bias; void* C;
  long sA, sB, sC;          // batch strides (elements)
  int K, lda, ldb, ldc;
  int gx, gy;               // block grid (z implied)
  int start;                // first linear block id of this segment
  int mode, outf;           // bias mode (0/1 col/2 row); 0 bf16 out, 1 fp32
  float scale;
};
struct GemmPack { GemmDesc d[6]; int nd; };

__global__ __launch_bounds__(256)
void gemm_multi_kernel(GemmPack p)
{
  __shared__ __align__(16) u16 Asl[128 * 32];
  __shared__ __align__(16) u16 Bsl[128 * 32];

  int seg = 0;
#pragma unroll
  for (int t = 1; t < 6; ++t)
    if (t < p.nd && (int)blockIdx.x >= p.d[t].start) seg = t;
  const GemmDesc& g = p.d[seg];
  const int local = (int)blockIdx.x - g.start;
  const int pxy = g.gx * g.gy;
  const int bz = local / pxy;
  const int rem = local - bz * pxy;
  const int by = rem / g.gx;
  const int bx = rem - by * g.gx;

  const int tid  = threadIdx.x;
  const int lane = tid & 63;
  const int wave = tid >> 6;
  const int l15  = lane & 15;
  const int quad = lane >> 4;
  const int mw   = (wave >> 1) * 64;
  const int nw   = (wave & 1) * 64;

  const char* Ab = (const char*)(g.A + (long)bz * g.sA + (long)bx * 128 * g.lda);
  const char* Bb = (const char*)(g.Bt + (long)bz * g.sB + (long)by * 128 * g.ldb);

  // staging map: LDS offset o = wave*1024 + lane*16 (+4096 round 2)
  // row = o>>6; lds chunk cl = (o>>4)&3; global chunk = cl ^ s(row).
  // (s(row+64) == s(row), so one base serves both halves.)
  const int o   = wave * 1024 + lane * 16;
  const int mst = o >> 6;
  const int cl  = (o >> 4) & 3;
  const int sst = (mst + (mst >> 2)) & 3;
  const int off = (cl ^ sst) << 4;
  char* ldsA = (char*)Asl + wave * 1024;  // wave-uniform base
  char* ldsB = (char*)Bsl + wave * 1024;
  const long ldaB = (long)g.lda * 2;
  const long ldbB = (long)g.ldb * 2;
  const char* pa0 = Ab + (long)mst * ldaB + off;
  const char* pb0 = Bb + (long)mst * ldbB + off;

  // fragment LDS indices (k-invariant): row m, swizzled chunk quad^s(m)
  int ia[4], ib[4];
#pragma unroll
  for (int i = 0; i < 4; ++i) {
    const int m = mw + i * 16 + l15;
    ia[i] = m * 4 + (quad ^ ((m + (m >> 2)) & 3));
    const int n = nw + i * 16 + l15;
    ib[i] = n * 4 + (quad ^ ((n + (n >> 2)) & 3));
  }

  f32x4 acc[4][4];
  {
    f32x4 zz = {0.f, 0.f, 0.f, 0.f};
#pragma unroll
    for (int i = 0; i < 4; ++i)
#pragma unroll
      for (int j = 0; j < 4; ++j) acc[i][j] = zz;
  }

  const int nk = g.K >> 5;
  for (int kk = 0; kk < nk; ++kk) {
    const long kb = (long)kk << 6;  // 32 elems * 2B
    cp16(ldsA,        pa0 + kb);
    cp16(ldsA + 4096, pa0 + kb + 64 * ldaB);
    cp16(ldsB,        pb0 + kb);
    cp16(ldsB + 4096, pb0 + kb + 64 * ldbB);
    __syncthreads();

    bf16x8 a[4], b[4];
    const bf16x8* As8 = (const bf16x8*)Asl;
    const bf16x8* Bs8 = (const bf16x8*)Bsl;
#pragma unroll
    for (int i = 0; i < 4; ++i) a[i] = As8[ia[i]];
#pragma unroll
    for (int j = 0; j < 4; ++j) b[j] = Bs8[ib[j]];
#pragma unroll
    for (int i = 0; i < 4; ++i)
#pragma unroll
      for (int j = 0; j < 4; ++j)
        acc[i][j] = __builtin_amdgcn_mfma_f32_16x16x32_bf16(a[i], b[j], acc[i][j], 0, 0, 0);
    __syncthreads();
  }

  // Epilogue. C/D layout (m89): col = lane&15, row = quad*4 + reg.
  const int brow = bx * 128 + mw + quad * 4;
  const int bcol = by * 128 + nw + l15;
  float cb[4];
  if (g.mode == 1) {
#pragma unroll
    for (int j = 0; j < 4; ++j) cb[j] = g.bias[bcol + j * 16];
  }
#pragma unroll
  for (int i = 0; i < 4; ++i) {
    const int r0 = brow + i * 16;
    float rb[4];
    if (g.mode == 2) {
#pragma unroll
      for (int r = 0; r < 4; ++r) rb[r] = g.bias[r0 + r];
    }
#pragma unroll
    for (int j = 0; j < 4; ++j) {
      const int col = bcol + j * 16;
#pragma unroll
      for (int r = 0; r < 4; ++r) {
        float x = acc[i][j][r] * g.scale;
        if (g.mode == 1) x += cb[j];
        if (g.mode == 2) x += rb[r];
        const long idx = (long)bz * g.sC + (long)(r0 + r) * g.ldc + col;
        if (g.outf) ((float*)g.C)[idx] = x;
        else        ((u16*)g.C)[idx] = f2bf(x);
      }
    }
  }
}

// ---------------------------------------------------------------------------
// fp32 -> bf16 convert for two tensors in one launch. 8 elems/thread.
// ---------------------------------------------------------------------------
__global__ __launch_bounds__(256)
void cvt2_bf16_kernel(const float* __restrict__ sa, u16* __restrict__ da, int n8a,
                      const float* __restrict__ sb, u16* __restrict__ db, int n8b)
{
  int idx = blockIdx.x * 256 + threadIdx.x;
  const float* src; u16* dst; int i;
  if (idx < n8a) { src = sa; dst = da; i = idx; }
  else           { src = sb; dst = db; i = idx - n8a; if (i >= n8b) return; }
  const float4* s4 = (const float4*)src;
  float4 a = s4[i * 2], b = s4[i * 2 + 1];
  uint4 o;
  o.x = (unsigned int)f2bf(a.x) | ((unsigned int)f2bf(a.y) << 16);
  o.y = (unsigned int)f2bf(a.z) | ((unsigned int)f2bf(a.w) << 16);
  o.z = (unsigned int)f2bf(b.x) | ((unsigned int)f2bf(b.y) << 16);
  o.w = (unsigned int)f2bf(b.z) | ((unsigned int)f2bf(b.w) << 16);
  ((uint4*)dst)[i] = o;
}

// ---------------------------------------------------------------------------
// Transpose + convert six 768x768 fp32 weights ([in,out] -> bf16 [out,in]).
// ---------------------------------------------------------------------------
__global__ void transpose6_kernel(const float* s0, const float* s1, const float* s2,
                                  const float* s3, const float* s4, const float* s5,
                                  u16* d0, u16* d1, u16* d2,
                                  u16* d3, u16* d4, u16* d5)
{
  __shared__ float t[32][33];
  const float* src; u16* dst;
  switch (blockIdx.z) {
    case 0: src = s0; dst = d0; break;
    case 1: src = s1; dst = d1; break;
    case 2: src = s2; dst = d2; break;
    case 3: src = s3; dst = d3; break;
    case 4: src = s4; dst = d4; break;
    default: src = s5; dst = d5; break;
  }
  const int tx = threadIdx.x, ty = threadIdx.y;
  const int x = blockIdx.x * 32 + tx;
  const int y0 = blockIdx.y * 32;
#pragma unroll
  for (int j = 0; j < 32; j += 8) t[ty + j][tx] = src[(long)(y0 + ty + j) * 768 + x];
  __syncthreads();
  const int x2 = y0 + tx;
#pragma unroll
  for (int j = 0; j < 32; j += 8)
    dst[(long)(blockIdx.x * 32 + ty + j) * 768 + x2] = f2bf(t[tx][ty + j]);
}

// ---------------------------------------------------------------------------
// In-place row softmax on bf16 rows of width NV*256; both S matrices in one
// launch: blocks [0,8192) -> S1 rows (4096 wide); rest -> S2 rows (2048).
// ---------------------------------------------------------------------------
template <int NV>
__device__ __forceinline__ void softmax_row(u16* row)
{
  __shared__ float red[8];
  const int tid  = threadIdx.x;
  const int lane = tid & 63;
  const int wave = tid >> 6;
  uint4* p4 = (uint4*)row;

  uint4 ld[NV / 8];
#pragma unroll
  for (int c = 0; c < NV / 8; ++c) ld[c] = p4[tid + c * 256];
  float v[NV];
#pragma unroll
  for (int c = 0; c < NV / 8; ++c) {
    unsigned int w[4] = {ld[c].x, ld[c].y, ld[c].z, ld[c].w};
#pragma unroll
    for (int q = 0; q < 4; ++q) {
      v[c * 8 + q * 2]     = bf2f((u16)(w[q] & 0xffffu));
      v[c * 8 + q * 2 + 1] = bf2f((u16)(w[q] >> 16));
    }
  }

  float m = -1e30f;
#pragma unroll
  for (int i = 0; i < NV; ++i) m = fmaxf(m, v[i]);
#pragma unroll
  for (int off = 32; off > 0; off >>= 1) m = fmaxf(m, __shfl_xor(m, off, 64));
  if (lane == 0) red[wave] = m;
  __syncthreads();
  m = fmaxf(fmaxf(red[0], red[1]), fmaxf(red[2], red[3]));

  float s = 0.f;
#pragma unroll
  for (int i = 0; i < NV; ++i) { v[i] = __expf(v[i] - m); s += v[i]; }
#pragma unroll
  for (int off = 32; off > 0; off >>= 1) s += __shfl_xor(s, off, 64);
  if (lane == 0) red[4 + wave] = s;
  __syncthreads();
  s = (red[4] + red[5]) + (red[6] + red[7]);
  const float inv = 1.0f / s;

#pragma unroll
  for (int c = 0; c < NV / 8; ++c) {
    unsigned int w[4];
#pragma unroll
    for (int q = 0; q < 4; ++q) {
      const u16 lo = f2bf(v[c * 8 + q * 2] * inv);
      const u16 hi = f2bf(v[c * 8 + q * 2 + 1] * inv);
      w[q] = (unsigned int)lo | ((unsigned int)hi << 16);
    }
    uint4 st; st.x = w[0]; st.y = w[1]; st.z = w[2]; st.w = w[3];
    p4[tid + c * 256] = st;
  }
}

__global__ __launch_bounds__(256)
void softmax_both_kernel(u16* S1, u16* S2)
{
  if (blockIdx.x < 8192) softmax_row<16>(S1 + (long)blockIdx.x * 4096);
  else                   softmax_row<8>(S2 + (long)(blockIdx.x - 8192) * 2048);
}

// ---------------------------------------------------------------------------

static GemmDesc mkdesc(const void* A, const void* Bt, const float* bias, void* C,
                       long sA, long sB, long sC, int K, int lda, int ldb, int ldc,
                       int M, int N, int start, int mode, int outf, float scale)
{
  GemmDesc d;
  d.A = (const u16*)A; d.Bt = (const u16*)Bt; d.bias = bias; d.C = C;
  d.sA = sA; d.sB = sB; d.sC = sC;
  d.K = K; d.lda = lda; d.ldb = ldb; d.ldc = ldc;
  d.gx = M / 128; d.gy = N / 128; d.start = start;
  d.mode = mode; d.outf = outf; d.scale = scale;
  return d;
}

extern "C" void kernel_launch(void* const* d_in, const int* in_sizes, int n_in,
                              void* d_out, int out_size, void* d_ws, size_t ws_size,
                              hipStream_t stream)
{
  (void)in_sizes; (void)n_in; (void)out_size; (void)ws_size;
  const float* syn = (const float*)d_in[0];   // [4,4096,768] fp32
  const float* sem = (const float*)d_in[1];   // [4,2048,768] fp32
  const float* W[6]    = {(const float*)d_in[2], (const float*)d_in[4],  (const float*)d_in[6],
                          (const float*)d_in[8], (const float*)d_in[10], (const float*)d_in[12]};
  const float* bias[6] = {(const float*)d_in[3], (const float*)d_in[5],  (const float*)d_in[7],
                          (const float*)d_in[9], (const float*)d_in[11], (const float*)d_in[13]};
  float* out = (float*)d_out;

  // ws arena (u16 offsets). Peak use 85,983,232 u16 = 171.97 MB.
  u16* ws   = (u16*)d_ws;
  u16* S1   = ws;                       // [0, 33,554,432)
  u16* synb = ws;                       //   [0, 12,582,912)   dead after PROJ
  u16* semb = ws + 12582912;            //   [.., 18,874,368)  dead after PROJ
  u16* WT   = ws + 18874368;            //   [.., 22,413,312)  dead after PROJ
  u16* S2   = ws + 33554432;            // [.., 67,108,864)
  u16* V1T  = ws + 67108864;            // [.., 79,691,776)    until O1
  u16* Q1   = ws + 79691776;            // [.., 85,983,232)    dead after S1
  u16* V2Tc = ws + 79691776;            //   V2T copy target (over dead Q1)
  // parked in outputs:
  u16* K1  = (u16*)out;                 // out0: 12,582,912 u16, dead after S1
  u16* o1  = (u16*)(out + 6291456);     // out1 region base
  u16* Q2  = o1;                        // 12,582,912 u16, dead after S2
  u16* K2  = o1 + 12582912;             //  6,291,456 u16, dead after S2
  u16* V2T = o1 + 18874368;             //  6,291,456 u16, copied out before O2

  const float SC = 0.036084391824351615f;  // 768^-0.5

  // D1) fp32 -> bf16 converts
  cvt2_bf16_kernel<<<dim3(9216), dim3(256), 0, stream>>>(
      syn, synb, 1572864, sem, semb, 786432);

  // D2) weight transpose+convert
  transpose6_kernel<<<dim3(24, 24, 6), dim3(32, 8, 1), 0, stream>>>(
      W[0], W[1], W[2], W[3], W[4], W[5],
      WT + 0 * 589824, WT + 1 * 589824, WT + 2 * 589824,
      WT + 3 * 589824, WT + 4 * 589824, WT + 5 * 589824);

  // D3) all six projections (3456 blocks)
  {
    GemmPack p; p.nd = 6;
    p.d[0] = mkdesc(synb, WT + 1 * 589824, bias[1], K1, 0, 0, 0,     // K1 -> out0
                    768, 768, 768, 768, 16384, 768, 0, 1, 0, 1.f);
    p.d[1] = mkdesc(synb, WT + 3 * 589824, bias[3], Q2, 0, 0, 0,     // Q2 -> out1
                    768, 768, 768, 768, 16384, 768, 768, 1, 0, 1.f);
    p.d[2] = mkdesc(WT + 2 * 589824, synb, bias[2], V1T, 0, 0, 0,    // V1T -> ws
                    768, 768, 768, 16384, 768, 16384, 1536, 2, 0, 1.f);
    p.d[3] = mkdesc(semb, WT + 0 * 589824, bias[0], Q1, 0, 0, 0,     // Q1 -> ws
                    768, 768, 768, 768, 8192, 768, 2304, 1, 0, 1.f);
    p.d[4] = mkdesc(semb, WT + 4 * 589824, bias[4], K2, 0, 0, 0,     // K2 -> out1
                    768, 768, 768, 768, 8192, 768, 2688, 1, 0, 1.f);
    p.d[5] = mkdesc(WT + 5 * 589824, semb, bias[5], V2T, 0, 0, 0,    // V2T -> out1
                    768, 768, 768, 8192, 768, 8192, 3072, 2, 0, 1.f);
    gemm_multi_kernel<<<dim3(3456), dim3(256), 0, stream>>>(p);
  }

  // D4) S1 + S2 (4096 blocks); S1 overwrites dead synb/semb/WT
  {
    GemmPack p; p.nd = 2;
    p.d[0] = mkdesc(Q1, K1, nullptr, S1,                             // [4][2048x4096]
                    1572864L, 3145728L, 8388608L,
                    768, 768, 768, 4096, 2048, 4096, 0, 0, 0, SC);
    p.d[1] = mkdesc(Q2, K2, nullptr, S2,                             // [4][4096x2048]
                    3145728L, 1572864L, 8388608L,
                    768, 768, 768, 2048, 4096, 2048, 2048, 0, 0, SC);
    gemm_multi_kernel<<<dim3(4096), dim3(256), 0, stream>>>(p);
  }

  // D5) softmax over all S1 and S2 rows (one launch)
  softmax_both_kernel<<<dim3(24576), dim3(256), 0, stream>>>(S1, S2);

  // D5.5) move V2T out of out1 (O2 will overwrite out1)
  hipMemcpyAsync(V2Tc, V2T, 12582912, hipMemcpyDeviceToDevice, stream);

  // D6) O1 + O2 (1152 blocks), fp32 -> d_out
  {
    GemmPack p; p.nd = 2;
    p.d[0] = mkdesc(S1, V1T, nullptr, out,                           // [4][2048x768]
                    8388608L, 4096L, 1572864L,
                    4096, 4096, 16384, 768, 2048, 768, 0, 0, 1, 1.f);
    p.d[1] = mkdesc(S2, V2Tc, nullptr, out + 6291456,                // [4][4096x768]
                    8388608L, 2048L, 3145728L,
                    2048, 2048, 8192, 768, 4096, 768, 384, 0, 1, 1.f);
    gemm_multi_kernel<<<dim3(1152), dim3(256), 0, stream>>>(p);
  }
}

// Round 5
// 581.932 us; speedup vs baseline: 1.2091x; 1.0890x over previous
//
#include <hip/hip_runtime.h>
#include <stdint.h>

// CrossAttention on MI355X (gfx950). fp32 I/O, bf16 MFMA compute.
// Round 5: (a) operand-swapped MFMA -> lane holds 4 consecutive C-cols ->
// vectorized coalesced epilogue stores; (b) BK=64 K-tile (128B LDS rows,
// XOR-chunk swizzle) -> half the barrier drains; (c) V2T evacuation folded
// into the softmax launch. Schedule: cvt -> Wt -> PROJx6 -> S1+S2 ->
// softmax(both)+copy -> O1+O2. Peak ws 171.97 MB (validated).

typedef unsigned short u16;
typedef __attribute__((ext_vector_type(8))) __bf16 bf16x8;
typedef __attribute__((ext_vector_type(4))) float f32x4;

__device__ __forceinline__ float bf2f(u16 u) {
  union { unsigned int i; float f; } x; x.i = ((unsigned int)u) << 16; return x.f;
}
__device__ __forceinline__ u16 f2bf(float f) {  // RNE
  union { float f; unsigned int i; } x; x.f = f;
  unsigned int i = x.i;
  i += 0x7fffu + ((i >> 16) & 1u);
  return (u16)(i >> 16);
}

// async global->LDS, 16B per lane. LDS dest is wave-uniform base + lane*16.
__device__ __forceinline__ void cp16(void* lds, const void* g) {
  __builtin_amdgcn_global_load_lds((__attribute__((address_space(1))) void*)g,
                                   (__attribute__((address_space(3))) void*)lds,
                                   16, 0, 0);
}

// ---------------------------------------------------------------------------
// Multi-GEMM, 128x128 tile, BK=64. C = scale*A·Bt^T (+bias); bf16/fp32 out.
// LDS rows = 64 elems (128 B, 8 chunks of 16 B); chunk c of row m stored at
// c ^ (m&7). Staging keeps wave-uniform base + lane*16 (global side permuted
// within the row). MFMA operands swapped: lane l15 = C-row, regs = 4 cols.
// ---------------------------------------------------------------------------
struct GemmDesc {
  const u16* A; const u16* Bt; const float* bias; void* C;
  long sA, sB, sC;          // batch strides (elements)
  int K, lda, ldb, ldc;
  int gx, gy;
  int start;
  int mode, outf;           // bias: 0 none/1 col/2 row; out: 0 bf16, 1 fp32
  float scale;
};
struct GemmPack { GemmDesc d[6]; int nd; };

__global__ __launch_bounds__(256)
void gemm_multi_kernel(GemmPack p)
{
  __shared__ __align__(16) u16 Asl[128 * 64];   // 16 KB
  __shared__ __align__(16) u16 Bsl[128 * 64];   // 16 KB

  int seg = 0;
#pragma unroll
  for (int t = 1; t < 6; ++t)
    if (t < p.nd && (int)blockIdx.x >= p.d[t].start) seg = t;
  const GemmDesc& g = p.d[seg];
  const int local = (int)blockIdx.x - g.start;
  const int pxy = g.gx * g.gy;
  const int bz = local / pxy;
  const int rem = local - bz * pxy;
  const int by = rem / g.gx;
  const int bx = rem - by * g.gx;

  const int tid  = threadIdx.x;
  const int lane = tid & 63;
  const int wave = tid >> 6;
  const int l15  = lane & 15;
  const int quad = lane >> 4;
  const int mw   = (wave >> 1) * 64;
  const int nw   = (wave & 1) * 64;

  const char* Ab = (const char*)(g.A + (long)bz * g.sA + (long)bx * 128 * g.lda);
  const char* Bb = (const char*)(g.Bt + (long)bz * g.sB + (long)by * 128 * g.ldb);

  // Staging: round r (r=0..3) covers rows [r*32, r*32+32).
  // o = r*4096 + wave*1024 + lane*16 -> row = r*32 + wave*8 + (lane>>3),
  // lds chunk = lane&7, global chunk = (lane&7) ^ (row&7), row&7 = lane>>3.
  const int srow  = wave * 8 + (lane >> 3);
  const int gchk  = (lane & 7) ^ (lane >> 3);
  const long ldaB = (long)g.lda * 2;
  const long ldbB = (long)g.ldb * 2;
  const char* pa00 = Ab + (long)srow * ldaB + (gchk << 4);
  const char* pb00 = Bb + (long)srow * ldbB + (gchk << 4);
  char* ldsA = (char*)Asl + wave * 1024;  // + r*4096, wave-uniform
  char* ldsB = (char*)Bsl + wave * 1024;

  // Fragment LDS indices (in bf16x8 units): row m, k-step s:
  // idx = m*8 + ((s*4+quad) ^ (m&7)), m&7 = l15&7.
  int ia[2][4], ib[2][4];
#pragma unroll
  for (int s = 0; s < 2; ++s)
#pragma unroll
    for (int i = 0; i < 4; ++i) {
      const int m = mw + i * 16 + l15;
      ia[s][i] = m * 8 + ((s * 4 + quad) ^ (l15 & 7));
      const int n = nw + i * 16 + l15;
      ib[s][i] = n * 8 + ((s * 4 + quad) ^ (l15 & 7));
    }

  f32x4 acc[4][4];
  {
    f32x4 zz = {0.f, 0.f, 0.f, 0.f};
#pragma unroll
    for (int i = 0; i < 4; ++i)
#pragma unroll
      for (int j = 0; j < 4; ++j) acc[i][j] = zz;
  }

  const int nk = g.K >> 6;
  for (int kk = 0; kk < nk; ++kk) {
    const long kb = (long)kk << 7;  // 64 elems * 2B along k
#pragma unroll
    for (int r = 0; r < 4; ++r) {
      cp16(ldsA + r * 4096, pa00 + kb + (long)r * 32 * ldaB);
      cp16(ldsB + r * 4096, pb00 + kb + (long)r * 32 * ldbB);
    }
    __syncthreads();

    const bf16x8* As8 = (const bf16x8*)Asl;
    const bf16x8* Bs8 = (const bf16x8*)Bsl;
#pragma unroll
    for (int s = 0; s < 2; ++s) {
      bf16x8 a[4], b[4];
#pragma unroll
      for (int i = 0; i < 4; ++i) a[i] = As8[ia[s][i]];
#pragma unroll
      for (int j = 0; j < 4; ++j) b[j] = Bs8[ib[s][j]];
      // swapped operands: D row-index <- Bt rows (cols n), col-index <- A rows.
#pragma unroll
      for (int i = 0; i < 4; ++i)
#pragma unroll
        for (int j = 0; j < 4; ++j)
          acc[i][j] = __builtin_amdgcn_mfma_f32_16x16x32_bf16(b[j], a[i], acc[i][j], 0, 0, 0);
    }
    __syncthreads();
  }

  // Epilogue (swapped layout): lane l15 = C row, regs = 4 consecutive cols.
  // row = bx*128 + mw + i*16 + l15; cols = by*128 + nw + j*16 + quad*4 + r.
  const long cbase = (long)bz * g.sC;
#pragma unroll
  for (int i = 0; i < 4; ++i) {
    const int row = bx * 128 + mw + i * 16 + l15;
    const float rbias = (g.mode == 2) ? g.bias[row] : 0.f;
#pragma unroll
    for (int j = 0; j < 4; ++j) {
      const int colbase = by * 128 + nw + j * 16 + quad * 4;
      float v[4];
#pragma unroll
      for (int r = 0; r < 4; ++r) v[r] = acc[i][j][r] * g.scale;
      if (g.mode == 1) {
        const float4 cb = *(const float4*)(g.bias + colbase);
        v[0] += cb.x; v[1] += cb.y; v[2] += cb.z; v[3] += cb.w;
      } else if (g.mode == 2) {
#pragma unroll
        for (int r = 0; r < 4; ++r) v[r] += rbias;
      }
      const long idx = cbase + (long)row * g.ldc + colbase;
      if (g.outf) {
        float4 st; st.x = v[0]; st.y = v[1]; st.z = v[2]; st.w = v[3];
        *(float4*)((float*)g.C + idx) = st;
      } else {
        uint2 st;
        st.x = (unsigned int)f2bf(v[0]) | ((unsigned int)f2bf(v[1]) << 16);
        st.y = (unsigned int)f2bf(v[2]) | ((unsigned int)f2bf(v[3]) << 16);
        *(uint2*)((u16*)g.C + idx) = st;
      }
    }
  }
}

// ---------------------------------------------------------------------------
// fp32 -> bf16 convert for two tensors in one launch. 8 elems/thread.
// ---------------------------------------------------------------------------
__global__ __launch_bounds__(256)
void cvt2_bf16_kernel(const float* __restrict__ sa, u16* __restrict__ da, int n8a,
                      const float* __restrict__ sb, u16* __restrict__ db, int n8b)
{
  int idx = blockIdx.x * 256 + threadIdx.x;
  const float* src; u16* dst; int i;
  if (idx < n8a) { src = sa; dst = da; i = idx; }
  else           { src = sb; dst = db; i = idx - n8a; if (i >= n8b) return; }
  const float4* s4 = (const float4*)src;
  float4 a = s4[i * 2], b = s4[i * 2 + 1];
  uint4 o;
  o.x = (unsigned int)f2bf(a.x) | ((unsigned int)f2bf(a.y) << 16);
  o.y = (unsigned int)f2bf(a.z) | ((unsigned int)f2bf(a.w) << 16);
  o.z = (unsigned int)f2bf(b.x) | ((unsigned int)f2bf(b.y) << 16);
  o.w = (unsigned int)f2bf(b.z) | ((unsigned int)f2bf(b.w) << 16);
  ((uint4*)dst)[i] = o;
}

// ---------------------------------------------------------------------------
// Transpose + convert six 768x768 fp32 weights ([in,out] -> bf16 [out,in]).
// ---------------------------------------------------------------------------
__global__ void transpose6_kernel(const float* s0, const float* s1, const float* s2,
                                  const float* s3, const float* s4, const float* s5,
                                  u16* d0, u16* d1, u16* d2,
                                  u16* d3, u16* d4, u16* d5)
{
  __shared__ float t[32][33];
  const float* src; u16* dst;
  switch (blockIdx.z) {
    case 0: src = s0; dst = d0; break;
    case 1: src = s1; dst = d1; break;
    case 2: src = s2; dst = d2; break;
    case 3: src = s3; dst = d3; break;
    case 4: src = s4; dst = d4; break;
    default: src = s5; dst = d5; break;
  }
  const int tx = threadIdx.x, ty = threadIdx.y;
  const int x = blockIdx.x * 32 + tx;
  const int y0 = blockIdx.y * 32;
#pragma unroll
  for (int j = 0; j < 32; j += 8) t[ty + j][tx] = src[(long)(y0 + ty + j) * 768 + x];
  __syncthreads();
  const int x2 = y0 + tx;
#pragma unroll
  for (int j = 0; j < 32; j += 8)
    dst[(long)(blockIdx.x * 32 + ty + j) * 768 + x2] = f2bf(t[tx][ty + j]);
}

// ---------------------------------------------------------------------------
// In-place row softmax (bf16) over S1 rows (4096 wide, 8192 rows) and S2 rows
// (2048 wide, 16384 rows), plus V2T evacuation copy, all in one launch.
// ---------------------------------------------------------------------------
template <int NV>
__device__ __forceinline__ void softmax_row(u16* row)
{
  __shared__ float red[8];
  const int tid  = threadIdx.x;
  const int lane = tid & 63;
  const int wave = tid >> 6;
  uint4* p4 = (uint4*)row;

  uint4 ld[NV / 8];
#pragma unroll
  for (int c = 0; c < NV / 8; ++c) ld[c] = p4[tid + c * 256];
  float v[NV];
#pragma unroll
  for (int c = 0; c < NV / 8; ++c) {
    unsigned int w[4] = {ld[c].x, ld[c].y, ld[c].z, ld[c].w};
#pragma unroll
    for (int q = 0; q < 4; ++q) {
      v[c * 8 + q * 2]     = bf2f((u16)(w[q] & 0xffffu));
      v[c * 8 + q * 2 + 1] = bf2f((u16)(w[q] >> 16));
    }
  }

  float m = -1e30f;
#pragma unroll
  for (int i = 0; i < NV; ++i) m = fmaxf(m, v[i]);
#pragma unroll
  for (int off = 32; off > 0; off >>= 1) m = fmaxf(m, __shfl_xor(m, off, 64));
  if (lane == 0) red[wave] = m;
  __syncthreads();
  m = fmaxf(fmaxf(red[0], red[1]), fmaxf(red[2], red[3]));

  float s = 0.f;
#pragma unroll
  for (int i = 0; i < NV; ++i) { v[i] = __expf(v[i] - m); s += v[i]; }
#pragma unroll
  for (int off = 32; off > 0; off >>= 1) s += __shfl_xor(s, off, 64);
  if (lane == 0) red[4 + wave] = s;
  __syncthreads();
  s = (red[4] + red[5]) + (red[6] + red[7]);
  const float inv = 1.0f / s;

#pragma unroll
  for (int c = 0; c < NV / 8; ++c) {
    unsigned int w[4];
#pragma unroll
    for (int q = 0; q < 4; ++q) {
      const u16 lo = f2bf(v[c * 8 + q * 2] * inv);
      const u16 hi = f2bf(v[c * 8 + q * 2 + 1] * inv);
      w[q] = (unsigned int)lo | ((unsigned int)hi << 16);
    }
    uint4 st; st.x = w[0]; st.y = w[1]; st.z = w[2]; st.w = w[3];
    p4[tid + c * 256] = st;
  }
}

__global__ __launch_bounds__(256)
void softmax_both_kernel(u16* S1, u16* S2, const u16* cpy_src, u16* cpy_dst)
{
  if (blockIdx.x < 8192) { softmax_row<16>(S1 + (long)blockIdx.x * 4096); return; }
  if (blockIdx.x < 24576) { softmax_row<8>(S2 + (long)(blockIdx.x - 8192) * 2048); return; }
  // copy blocks: 1536 blocks x 8 KB = 12,582,912 B (V2T out of out1)
  const long base = (long)(blockIdx.x - 24576) * 512 + threadIdx.x;
  const uint4* s = (const uint4*)cpy_src;
  uint4* d = (uint4*)cpy_dst;
  d[base] = s[base];
  d[base + 256] = s[base + 256];
}

// ---------------------------------------------------------------------------

static GemmDesc mkdesc(const void* A, const void* Bt, const float* bias, void* C,
                       long sA, long sB, long sC, int K, int lda, int ldb, int ldc,
                       int M, int N, int start, int mode, int outf, float scale)
{
  GemmDesc d;
  d.A = (const u16*)A; d.Bt = (const u16*)Bt; d.bias = bias; d.C = C;
  d.sA = sA; d.sB = sB; d.sC = sC;
  d.K = K; d.lda = lda; d.ldb = ldb; d.ldc = ldc;
  d.gx = M / 128; d.gy = N / 128; d.start = start;
  d.mode = mode; d.outf = outf; d.scale = scale;
  return d;
}

extern "C" void kernel_launch(void* const* d_in, const int* in_sizes, int n_in,
                              void* d_out, int out_size, void* d_ws, size_t ws_size,
                              hipStream_t stream)
{
  (void)in_sizes; (void)n_in; (void)out_size; (void)ws_size;
  const float* syn = (const float*)d_in[0];   // [4,4096,768] fp32
  const float* sem = (const float*)d_in[1];   // [4,2048,768] fp32
  const float* W[6]    = {(const float*)d_in[2], (const float*)d_in[4],  (const float*)d_in[6],
                          (const float*)d_in[8], (const float*)d_in[10], (const float*)d_in[12]};
  const float* bias[6] = {(const float*)d_in[3], (const float*)d_in[5],  (const float*)d_in[7],
                          (const float*)d_in[9], (const float*)d_in[11], (const float*)d_in[13]};
  float* out = (float*)d_out;

  // ws arena (u16 offsets). Peak use 85,983,232 u16 = 171.97 MB.
  u16* ws   = (u16*)d_ws;
  u16* S1   = ws;                       // [0, 33,554,432)
  u16* synb = ws;                       //   [0, 12,582,912)   dead after PROJ
  u16* semb = ws + 12582912;            //   [.., 18,874,368)  dead after PROJ
  u16* WT   = ws + 18874368;            //   [.., 22,413,312)  dead after PROJ
  u16* S2   = ws + 33554432;            // [.., 67,108,864)
  u16* V1T  = ws + 67108864;            // [.., 79,691,776)    until O1
  u16* Q1   = ws + 79691776;            // [.., 85,983,232)    dead after S1
  u16* V2Tc = ws + 79691776;            //   V2T copy target (over dead Q1)
  // parked in outputs:
  u16* K1  = (u16*)out;                 // out0: 12,582,912 u16, dead after S1
  u16* o1  = (u16*)(out + 6291456);     // out1 region base
  u16* Q2  = o1;                        // 12,582,912 u16, dead after S2
  u16* K2  = o1 + 12582912;             //  6,291,456 u16, dead after S2
  u16* V2T = o1 + 18874368;             //  6,291,456 u16, evacuated in D5

  const float SC = 0.036084391824351615f;  // 768^-0.5

  // D1) fp32 -> bf16 converts
  cvt2_bf16_kernel<<<dim3(9216), dim3(256), 0, stream>>>(
      syn, synb, 1572864, sem, semb, 786432);

  // D2) weight transpose+convert
  transpose6_kernel<<<dim3(24, 24, 6), dim3(32, 8, 1), 0, stream>>>(
      W[0], W[1], W[2], W[3], W[4], W[5],
      WT + 0 * 589824, WT + 1 * 589824, WT + 2 * 589824,
      WT + 3 * 589824, WT + 4 * 589824, WT + 5 * 589824);

  // D3) all six projections (3456 blocks)
  {
    GemmPack p; p.nd = 6;
    p.d[0] = mkdesc(synb, WT + 1 * 589824, bias[1], K1, 0, 0, 0,     // K1 -> out0
                    768, 768, 768, 768, 16384, 768, 0, 1, 0, 1.f);
    p.d[1] = mkdesc(synb, WT + 3 * 589824, bias[3], Q2, 0, 0, 0,     // Q2 -> out1
                    768, 768, 768, 768, 16384, 768, 768, 1, 0, 1.f);
    p.d[2] = mkdesc(WT + 2 * 589824, synb, bias[2], V1T, 0, 0, 0,    // V1T -> ws
                    768, 768, 768, 16384, 768, 16384, 1536, 2, 0, 1.f);
    p.d[3] = mkdesc(semb, WT + 0 * 589824, bias[0], Q1, 0, 0, 0,     // Q1 -> ws
                    768, 768, 768, 768, 8192, 768, 2304, 1, 0, 1.f);
    p.d[4] = mkdesc(semb, WT + 4 * 589824, bias[4], K2, 0, 0, 0,     // K2 -> out1
                    768, 768, 768, 768, 8192, 768, 2688, 1, 0, 1.f);
    p.d[5] = mkdesc(WT + 5 * 589824, semb, bias[5], V2T, 0, 0, 0,    // V2T -> out1
                    768, 768, 768, 8192, 768, 8192, 3072, 2, 0, 1.f);
    gemm_multi_kernel<<<dim3(3456), dim3(256), 0, stream>>>(p);
  }

  // D4) S1 + S2 (4096 blocks); S1 overwrites dead synb/semb/WT
  {
    GemmPack p; p.nd = 2;
    p.d[0] = mkdesc(Q1, K1, nullptr, S1,                             // [4][2048x4096]
                    1572864L, 3145728L, 8388608L,
                    768, 768, 768, 4096, 2048, 4096, 0, 0, 0, SC);
    p.d[1] = mkdesc(Q2, K2, nullptr, S2,                             // [4][4096x2048]
                    3145728L, 1572864L, 8388608L,
                    768, 768, 768, 2048, 4096, 2048, 2048, 0, 0, SC);
    gemm_multi_kernel<<<dim3(4096), dim3(256), 0, stream>>>(p);
  }

  // D5) softmax over all S rows + V2T evacuation (one launch)
  softmax_both_kernel<<<dim3(26112), dim3(256), 0, stream>>>(S1, S2, V2T, V2Tc);

  // D6) O1 + O2 (1152 blocks), fp32 -> d_out
  {
    GemmPack p; p.nd = 2;
    p.d[0] = mkdesc(S1, V1T, nullptr, out,                           // [4][2048x768]
                    8388608L, 4096L, 1572864L,
                    4096, 4096, 16384, 768, 2048, 768, 0, 0, 1, 1.f);
    p.d[1] = mkdesc(S2, V2Tc, nullptr, out + 6291456,                // [4][4096x768]
                    8388608L, 2048L, 3145728L,
                    2048, 2048, 8192, 768, 4096, 768, 384, 0, 1, 1.f);
    gemm_multi_kernel<<<dim3(1152), dim3(256), 0, stream>>>(p);
  }
}